// Round 3
// baseline (2064.865 us; speedup 1.0000x reference)
//
#include <hip/hip_runtime.h>

#define B_ 16
#define S_ 512
#define T_ 2048
#define D_ 256
#define H_ 128

typedef __attribute__((ext_vector_type(8))) short s8v;    // 8 x bf16 (bit pattern)
typedef __attribute__((ext_vector_type(4))) float f4v;    // 4 x f32

// ---------------- workspace layout (floats) ----------------
#define WS_C     0          // c centers [B,S] : 8192
#define WS_W2    8192       // w2 [B,T] : 32768
#define WS_FRAG  40960      // Whh bf16 fragments [2 layers][131072 ushort] = 262144 ushort
#define WS_XG    303104     // Xg [dir][s][n][b] fp32 : 8388608
#define WS_H1    8691712    // H [s][b][256] fp32 : 2097152

// ---------------- output layout (floats) ----------------
#define OUT_MAIN   0          // [B,T,D]  8388608
#define OUT_LOGDUR 8388608    // [B,S]    8192
#define OUT_DUR    8396800    // [B,S]    8192
#define OUT_W      8404992    // [B,S,T]  16777216

__device__ __forceinline__ unsigned short f2bf(float f) {
    union { float f; unsigned u; } v; v.f = f;
    unsigned r = v.u + 0x7fffu + ((v.u >> 16) & 1u);
    return (unsigned short)(r >> 16);
}
__device__ __forceinline__ float sigf(float x) { return 1.f / (1.f + __expf(-x)); }
__device__ __forceinline__ float tanhfast(float x) {
    float xc = fmaxf(x, -15.f);
    float e = __expf(-2.f * xc);
    return (1.f - e) / (1.f + e);
}

// ============ prep: cumsum -> centers, copy duration ============
__global__ void prep_kernel(const float* __restrict__ dur, float* __restrict__ c,
                            float* __restrict__ out_dur) {
    int b = blockIdx.x;
    int s = threadIdx.x;
    __shared__ float sc[S_];
    float d = dur[b * S_ + s];
    sc[s] = d;
    __syncthreads();
    float v = d;
    for (int off = 1; off < S_; off <<= 1) {
        float add = (s >= off) ? sc[s - off] : 0.f;
        __syncthreads();
        v += add;
        sc[s] = v;
        __syncthreads();
    }
    c[b * S_ + s] = v - 0.5f * d;
    out_dur[b * S_ + s] = d;
}

// ============ Whh -> bf16 MFMA B-fragments ============
__global__ void whh_frag_kernel(const float* __restrict__ Whh0, const float* __restrict__ Whh1,
                                unsigned short* __restrict__ frags) {
    int idx = blockIdx.x * 256 + threadIdx.x;  // 262144
    int j = idx & 7, l = (idx >> 3) & 63, kc = (idx >> 9) & 3, tn = (idx >> 11) & 31;
    int dir = (idx >> 16) & 1, layer = (idx >> 17) & 1;
    int n = tn * 16 + (l & 15);
    int k = kc * 32 + (l >> 4) * 8 + j;
    const float* W = layer ? Whh1 : Whh0;
    frags[idx] = f2bf(W[dir * 65536 + n * 128 + k]);
}

// ============ gemm: Xg[dir][s][n][b] = A[m,:256] . Wih[n,:256] + bias[n] ============
// sb==0: m = b*512+s (x layout); sb==1: m = s*16+b (H1 layout)
#define BM 64
#define BN 64
#define BK 64
__global__ __launch_bounds__(256) void gemm_xg_kernel(const float* __restrict__ A,
                                                      const float* __restrict__ Bw,
                                                      const float* __restrict__ bias,
                                                      float* __restrict__ Xg, int sb) {
    __shared__ float As[BK][BM + 4];
    __shared__ float Bs[BK][BN + 4];
    int tid = threadIdx.x;
    int m0 = blockIdx.x * BM;
    int n0 = blockIdx.y * BN;
    int tm = tid >> 4, tn = tid & 15;
    float acc[4][4] = {};
    for (int k0 = 0; k0 < 256; k0 += BK) {
#pragma unroll
        for (int i = 0; i < 4; i++) {
            int p = tid + 256 * i;
            int m = p >> 4, kq = p & 15;
            float4 av = *reinterpret_cast<const float4*>(&A[(size_t)(m0 + m) * 256 + k0 + 4 * kq]);
            As[4 * kq + 0][m] = av.x; As[4 * kq + 1][m] = av.y;
            As[4 * kq + 2][m] = av.z; As[4 * kq + 3][m] = av.w;
            float4 bv = *reinterpret_cast<const float4*>(&Bw[(size_t)(n0 + m) * 256 + k0 + 4 * kq]);
            Bs[4 * kq + 0][m] = bv.x; Bs[4 * kq + 1][m] = bv.y;
            Bs[4 * kq + 2][m] = bv.z; Bs[4 * kq + 3][m] = bv.w;
        }
        __syncthreads();
#pragma unroll
        for (int k = 0; k < BK; k++) {
            float4 a4 = *reinterpret_cast<const float4*>(&As[k][4 * tm]);
            float4 b4 = *reinterpret_cast<const float4*>(&Bs[k][4 * tn]);
            float av[4] = {a4.x, a4.y, a4.z, a4.w};
            float bv[4] = {b4.x, b4.y, b4.z, b4.w};
#pragma unroll
            for (int i = 0; i < 4; i++)
#pragma unroll
                for (int j = 0; j < 4; j++) acc[i][j] += av[i] * bv[j];
        }
        __syncthreads();
    }
#pragma unroll
    for (int i = 0; i < 4; i++) {
        int m = m0 + 4 * tm + i;
        int b, s;
        if (sb) { s = m >> 4; b = m & 15; } else { b = m >> 9; s = m & 511; }
#pragma unroll
        for (int jx = 0; jx < 4; jx++) {
            int n = n0 + 4 * tn + jx;
            int dir = n >> 9, jj = n & 511;
            Xg[((size_t)(dir * 512 + s) * 512 + jj) * 16 + b] = acc[i][jx] + bias[n];
        }
    }
}

// ============ MFMA LSTM scan body: raw barriers + counted vmcnt, 4-deep xg pipe ============
// Block = one direction, all 16 batches. G[16,512] = H[16,128] @ WhhT per step.
// Hout (f32) layout: [s][b][256], dir slice at dir*128.
#define SCAN_STEP(PIPE, WAIT_ASM, T)                                              \
  {                                                                               \
    int s_ = dir ? 511 - (T) : (T);                                               \
    asm volatile(WAIT_ASM ::: "memory");                                          \
    __builtin_amdgcn_sched_barrier(0);                                            \
    f4v acc0 = PIPE[0], acc1 = PIPE[1], acc2 = PIPE[2], acc3 = PIPE[3];           \
    int t4_ = (T) + 4; if (t4_ > 511) t4_ = 511;                                  \
    int s4_ = dir ? 511 - t4_ : t4_;                                              \
    PIPE[0] = *(const f4v*)(xg_dir + (size_t)s4_ * 8192 + 0 * 2048 + lane_off);   \
    PIPE[1] = *(const f4v*)(xg_dir + (size_t)s4_ * 8192 + 1 * 2048 + lane_off);   \
    PIPE[2] = *(const f4v*)(xg_dir + (size_t)s4_ * 8192 + 2 * 2048 + lane_off);   \
    PIPE[3] = *(const f4v*)(xg_dir + (size_t)s4_ * 8192 + 3 * 2048 + lane_off);   \
    __builtin_amdgcn_sched_barrier(0);                                            \
    const unsigned short* hrow_ = Hb + ((T) & 1) * 2176 + col * 136 + lg * 8;     \
    s8v a0 = *(const s8v*)(hrow_);                                                \
    s8v a1 = *(const s8v*)(hrow_ + 32);                                           \
    s8v a2 = *(const s8v*)(hrow_ + 64);                                           \
    s8v a3 = *(const s8v*)(hrow_ + 96);                                           \
    asm volatile("s_waitcnt lgkmcnt(0)" ::: "memory");                            \
    __builtin_amdgcn_sched_barrier(0);                                            \
    acc0 = __builtin_amdgcn_mfma_f32_16x16x32_bf16(a0, bf[0][0], acc0, 0, 0, 0);  \
    acc1 = __builtin_amdgcn_mfma_f32_16x16x32_bf16(a0, bf[1][0], acc1, 0, 0, 0);  \
    acc2 = __builtin_amdgcn_mfma_f32_16x16x32_bf16(a0, bf[2][0], acc2, 0, 0, 0);  \
    acc3 = __builtin_amdgcn_mfma_f32_16x16x32_bf16(a0, bf[3][0], acc3, 0, 0, 0);  \
    acc0 = __builtin_amdgcn_mfma_f32_16x16x32_bf16(a1, bf[0][1], acc0, 0, 0, 0);  \
    acc1 = __builtin_amdgcn_mfma_f32_16x16x32_bf16(a1, bf[1][1], acc1, 0, 0, 0);  \
    acc2 = __builtin_amdgcn_mfma_f32_16x16x32_bf16(a1, bf[2][1], acc2, 0, 0, 0);  \
    acc3 = __builtin_amdgcn_mfma_f32_16x16x32_bf16(a1, bf[3][1], acc3, 0, 0, 0);  \
    acc0 = __builtin_amdgcn_mfma_f32_16x16x32_bf16(a2, bf[0][2], acc0, 0, 0, 0);  \
    acc1 = __builtin_amdgcn_mfma_f32_16x16x32_bf16(a2, bf[1][2], acc1, 0, 0, 0);  \
    acc2 = __builtin_amdgcn_mfma_f32_16x16x32_bf16(a2, bf[2][2], acc2, 0, 0, 0);  \
    acc3 = __builtin_amdgcn_mfma_f32_16x16x32_bf16(a2, bf[3][2], acc3, 0, 0, 0);  \
    acc0 = __builtin_amdgcn_mfma_f32_16x16x32_bf16(a3, bf[0][3], acc0, 0, 0, 0);  \
    acc1 = __builtin_amdgcn_mfma_f32_16x16x32_bf16(a3, bf[1][3], acc1, 0, 0, 0);  \
    acc2 = __builtin_amdgcn_mfma_f32_16x16x32_bf16(a3, bf[2][3], acc2, 0, 0, 0);  \
    acc3 = __builtin_amdgcn_mfma_f32_16x16x32_bf16(a3, bf[3][3], acc3, 0, 0, 0);  \
    unsigned short* Hnxt_ = Hb + (((T) + 1) & 1) * 2176;                          \
    _Pragma("unroll")                                                             \
    for (int r = 0; r < 4; r++) {                                                 \
      float i_ = acc0[r], f_ = acc1[r], g_ = acc2[r], o_ = acc3[r];               \
      float cn = sigf(f_) * c4[r] + sigf(i_) * tanhfast(g_);                      \
      c4[r] = cn;                                                                 \
      float h_ = sigf(o_) * tanhfast(cn);                                         \
      Hnxt_[(lg * 4 + r) * 136 + hidx] = f2bf(h_);                                \
      Hout[((size_t)(s_ * 16 + lg * 4 + r)) * 256 + dir * 128 + hidx] = h_;       \
    }                                                                             \
    __builtin_amdgcn_sched_barrier(0);                                            \
    asm volatile("s_waitcnt lgkmcnt(0)" ::: "memory");                            \
    __builtin_amdgcn_s_barrier();                                                 \
  }

__device__ void lstm_scan_body(const float* __restrict__ Xg,
                               const unsigned short* __restrict__ frags,
                               float* __restrict__ Hout, char* smem, int dir) {
    int tid = threadIdx.x;
    int w = tid >> 6, l = tid & 63;
    int col = l & 15, lg = l >> 4;
    int hidx = w * 16 + col;
    unsigned short* Hb = (unsigned short*)smem;  // [2][16][136] bf16

    // B-fragments (16 global s8v loads)
    s8v bf[4][4];
#pragma unroll
    for (int q = 0; q < 4; q++)
#pragma unroll
        for (int kc = 0; kc < 4; kc++) {
            int tn = q * 8 + w;
            bf[q][kc] = *(const s8v*)&frags[(((dir * 32 + tn) * 4 + kc) * 64 + l) * 8];
        }
    asm volatile("s_waitcnt vmcnt(0)" ::: "memory");
    __builtin_amdgcn_sched_barrier(0);

    for (int i = tid; i < 2 * 16 * 136; i += 512) Hb[i] = 0;

    const float* xg_dir = Xg + (size_t)dir * (512 * 512 * 16);
    int lane_off = (w * 16 + col) * 16 + lg * 4;

    f4v pipe0[4], pipe1[4], pipe2[4], pipe3[4];
    {
        int t0 = dir ? 511 : 0, t1 = dir ? 510 : 1, t2 = dir ? 509 : 2, t3 = dir ? 508 : 3;
#pragma unroll
        for (int q = 0; q < 4; q++) pipe0[q] = *(const f4v*)(xg_dir + (size_t)t0 * 8192 + q * 2048 + lane_off);
        __builtin_amdgcn_sched_barrier(0);
#pragma unroll
        for (int q = 0; q < 4; q++) pipe1[q] = *(const f4v*)(xg_dir + (size_t)t1 * 8192 + q * 2048 + lane_off);
        __builtin_amdgcn_sched_barrier(0);
#pragma unroll
        for (int q = 0; q < 4; q++) pipe2[q] = *(const f4v*)(xg_dir + (size_t)t2 * 8192 + q * 2048 + lane_off);
        __builtin_amdgcn_sched_barrier(0);
#pragma unroll
        for (int q = 0; q < 4; q++) pipe3[q] = *(const f4v*)(xg_dir + (size_t)t3 * 8192 + q * 2048 + lane_off);
        __builtin_amdgcn_sched_barrier(0);
    }
    f4v c4 = {0.f, 0.f, 0.f, 0.f};
    asm volatile("s_waitcnt lgkmcnt(0)" ::: "memory");
    __builtin_amdgcn_s_barrier();

    SCAN_STEP(pipe0, "s_waitcnt vmcnt(12)", 0);
    SCAN_STEP(pipe1, "s_waitcnt vmcnt(16)", 1);
    SCAN_STEP(pipe2, "s_waitcnt vmcnt(20)", 2);
    SCAN_STEP(pipe3, "s_waitcnt vmcnt(24)", 3);
    for (int it = 1; it < 128; it++) {
        int t = it * 4;
        SCAN_STEP(pipe0, "s_waitcnt vmcnt(28)", t);
        SCAN_STEP(pipe1, "s_waitcnt vmcnt(28)", t + 1);
        SCAN_STEP(pipe2, "s_waitcnt vmcnt(28)", t + 2);
        SCAN_STEP(pipe3, "s_waitcnt vmcnt(28)", t + 3);
    }
}

// ============ w-write body (fused into layer-0 scan launch) ============
__device__ void wwrite_body(const float* __restrict__ c, const float* __restrict__ w2,
                            float* __restrict__ wout, int gb) {
    int base = (gb * 512 + (int)threadIdx.x) * 8;
    int t0 = base & 2047;
    int bs = base >> 11;
    int b = bs >> 9;
    float cv = c[bs];
    float4 w2a = *(const float4*)&w2[b * 2048 + t0];
    float4 w2b = *(const float4*)&w2[b * 2048 + t0 + 4];
    float r[8];
#pragma unroll
    for (int i = 0; i < 8; i++) {
        float d = (float)(t0 + 1 + i) - cv;
        r[i] = __expf(-0.1f * d * d);
    }
    float4 o1 = {r[0] / w2a.x, r[1] / w2a.y, r[2] / w2a.z, r[3] / w2a.w};
    float4 o2 = {r[4] / w2b.x, r[5] / w2b.y, r[6] / w2b.z, r[7] / w2b.w};
    *(float4*)&wout[base] = o1;
    *(float4*)&wout[base + 4] = o2;
}

// ============ einsum GEMM body, 512 threads, 128(t)x64(d) tile ============
__device__ void gemm_out_body(const float* __restrict__ wmat, const float* __restrict__ x,
                              float* __restrict__ out, int gb, char* smem) {
    int tt = gb & 15, dd = (gb >> 4) & 3, b = gb >> 6;
    int m0 = tt * 128, n0 = dd * 64;
    float* As = (float*)smem;        // [64][132]
    float* Bs = As + 64 * 132;       // [64][68]
    const float* wb = wmat + (size_t)b * (512 * 2048);
    const float* xb = x + (size_t)b * (512 * 256);
    int tid = threadIdx.x;
    int tm = tid >> 4, tn = tid & 15;
    float acc[4][4] = {};
    for (int k0 = 0; k0 < 512; k0 += 64) {
#pragma unroll
        for (int i = 0; i < 4; i++) {
            int p = tid + 512 * i;
            int kk = p >> 5, mq = p & 31;
            *(float4*)&As[kk * 132 + 4 * mq] =
                *(const float4*)&wb[(size_t)(k0 + kk) * 2048 + m0 + 4 * mq];
        }
#pragma unroll
        for (int i = 0; i < 2; i++) {
            int p = tid + 512 * i;
            int kk = p >> 4, nq = p & 15;
            *(float4*)&Bs[kk * 68 + 4 * nq] =
                *(const float4*)&xb[(size_t)(k0 + kk) * 256 + n0 + 4 * nq];
        }
        __syncthreads();
#pragma unroll
        for (int k = 0; k < 64; k++) {
            float4 a4 = *(const float4*)&As[k * 132 + 4 * tm];
            float4 b4 = *(const float4*)&Bs[k * 68 + 4 * tn];
            float av[4] = {a4.x, a4.y, a4.z, a4.w};
            float bv[4] = {b4.x, b4.y, b4.z, b4.w};
#pragma unroll
            for (int i = 0; i < 4; i++)
#pragma unroll
                for (int j = 0; j < 4; j++) acc[i][j] += av[i] * bv[j];
        }
        __syncthreads();
    }
#pragma unroll
    for (int i = 0; i < 4; i++) {
        int m = m0 + 4 * tm + i;
        float4 o = {acc[i][0], acc[i][1], acc[i][2], acc[i][3]};
        *(float4*)&out[((size_t)b * 2048 + m) * 256 + n0 + 4 * tn] = o;
    }
}

// ============ fused launches ============
__global__ __launch_bounds__(512) void fusedA_kernel(const float* __restrict__ Xg,
                                                     const unsigned short* __restrict__ frags,
                                                     float* __restrict__ H1,
                                                     const float* __restrict__ c,
                                                     const float* __restrict__ w2,
                                                     float* __restrict__ out_w) {
    extern __shared__ char smem[];
    if (blockIdx.x < 2) lstm_scan_body(Xg, frags, H1, smem, blockIdx.x);
    else wwrite_body(c, w2, out_w, blockIdx.x - 2);
}

__global__ __launch_bounds__(512) void fusedB_kernel(const float* __restrict__ Xg,
                                                     const unsigned short* __restrict__ frags,
                                                     float* __restrict__ H1,
                                                     const float* __restrict__ wmat,
                                                     const float* __restrict__ x,
                                                     float* __restrict__ out_main) {
    extern __shared__ char smem[];
    if (blockIdx.x < 2) lstm_scan_body(Xg, frags, H1, smem, blockIdx.x);
    else gemm_out_body(wmat, x, out_main, blockIdx.x - 2, smem);
}

// ============ projection: log_dur (reads H1 [s][b][256] f32) ============
__global__ void proj_kernel(const float* __restrict__ H1, const float* __restrict__ pw,
                            const float* __restrict__ pb, const unsigned char* __restrict__ mask,
                            float* __restrict__ out) {
    int rr = blockIdx.x * 4 + (threadIdx.x >> 6);  // b*512+s
    int lane = threadIdx.x & 63;
    int b = rr >> 9, s = rr & 511;
    float4 h = *reinterpret_cast<const float4*>(&H1[(size_t)(s * 16 + b) * 256 + lane * 4]);
    float4 w = *reinterpret_cast<const float4*>(&pw[lane * 4]);
    float v = h.x * w.x + h.y * w.y + h.z * w.z + h.w * w.w;
#pragma unroll
    for (int off = 32; off; off >>= 1) v += __shfl_xor(v, off);
    if (lane == 0) {
        float r = v + pb[0];
        r = r > 0.f ? r : 0.f;
        if (mask[rr]) r = 0.f;
        out[rr] = r;
    }
}

// ============ w2[b,t] = sum_s exp(-0.1 (t+1-c)^2) ============
__global__ void wsum_kernel(const float* __restrict__ c, float* __restrict__ w2) {
    int idx = blockIdx.x * 4 + (threadIdx.x >> 6);
    int lane = threadIdx.x & 63;
    int b = idx >> 11, t = idx & 2047;
    float tv = (float)(t + 1);
    const float* cb = c + b * 512;
    float sum = 0.f;
#pragma unroll
    for (int i = 0; i < 8; i++) {
        float d = tv - cb[lane + 64 * i];
        sum += __expf(-0.1f * d * d);
    }
#pragma unroll
    for (int off = 32; off; off >>= 1) sum += __shfl_xor(sum, off);
    if (lane == 0) w2[idx] = (sum == 0.f) ? 1.f : sum;
}

extern "C" void kernel_launch(void* const* d_in, const int* in_sizes, int n_in,
                              void* d_out, int out_size, void* d_ws, size_t ws_size,
                              hipStream_t stream) {
    const float* x = (const float*)d_in[0];
    const unsigned char* mask = (const unsigned char*)d_in[1];
    const float* dur = (const float*)d_in[2];
    const float* Wih0 = (const float*)d_in[3];
    const float* Whh0 = (const float*)d_in[4];
    const float* b0 = (const float*)d_in[5];
    const float* Wih1 = (const float*)d_in[6];
    const float* Whh1 = (const float*)d_in[7];
    const float* b1 = (const float*)d_in[8];
    const float* pw = (const float*)d_in[9];
    const float* pb = (const float*)d_in[10];

    float* out = (float*)d_out;
    float* ws = (float*)d_ws;
    float* c = ws + WS_C;
    float* w2 = ws + WS_W2;
    unsigned short* frags = (unsigned short*)(ws + WS_FRAG);
    float* Xg = ws + WS_XG;
    float* H1 = ws + WS_H1;

    float* out_main = out + OUT_MAIN;
    float* out_logdur = out + OUT_LOGDUR;
    float* out_dur = out + OUT_DUR;
    float* out_w = out + OUT_W;

    // ---- prep: centers, duration copy, Whh fragments, w2 ----
    prep_kernel<<<16, 512, 0, stream>>>(dur, c, out_dur);
    whh_frag_kernel<<<1024, 256, 0, stream>>>(Whh0, Whh1, frags);
    wsum_kernel<<<8192, 256, 0, stream>>>(c, w2);

    // ---- layer 0: Xg gemm (A = x, m = b*512+s), then scan fused with w-write ----
    gemm_xg_kernel<<<dim3(128, 16), 256, 0, stream>>>(x, Wih0, b0, Xg, 0);
    fusedA_kernel<<<2 + 4096, 512, 8704, stream>>>(Xg, frags, H1, c, w2, out_w);

    // ---- layer 1: Xg gemm (A = H1, m = s*16+b), then scan fused with einsum GEMM ----
    gemm_xg_kernel<<<dim3(128, 16), 256, 0, stream>>>(H1, Wih1, b1, Xg, 1);
    fusedB_kernel<<<2 + 1024, 512, 51200, stream>>>(Xg, frags + 131072, H1, out_w, x, out_main);

    // ---- projection ----
    proj_kernel<<<2048, 256, 0, stream>>>(H1, pw, pb, mask, out_logdur);
}

// Round 4
// 842.882 us; speedup vs baseline: 2.4498x; 2.4498x over previous
//
#include <hip/hip_runtime.h>

#define B_ 16
#define S_ 512
#define T_ 2048
#define D_ 256
#define H_ 128

typedef _Float16 half2_t __attribute__((ext_vector_type(2)));
union U32H2 { unsigned u; half2_t h; };

// ---------------- workspace layout (floats) ----------------
#define WS_C     0          // c centers [B,S] : 8192
#define WS_W2    8192       // w2 [B,T] : 32768
#define WS_WPK   40960      // Whh f16-pair pack [2][2][512][64] uint : 131072 uints
#define WS_XG    303104     // Xg [dir][s][b][512] fp32 : 8388608
#define WS_H1    8691712    // H [b][s][256] fp32 : 2097152

// ---------------- output layout (floats) ----------------
#define OUT_MAIN   0          // [B,T,D]  8388608
#define OUT_LOGDUR 8388608    // [B,S]    8192
#define OUT_DUR    8396800    // [B,S]    8192
#define OUT_W      8404992    // [B,S,T]  16777216

__device__ __forceinline__ float sigf(float x) { return 1.f / (1.f + __expf(-x)); }
__device__ __forceinline__ float tanhfast(float x) {
    float xc = fmaxf(x, -15.f);
    float e = __expf(-2.f * xc);
    return (1.f - e) / (1.f + e);
}

// ============ prep: cumsum -> centers, copy duration ============
__global__ void prep_kernel(const float* __restrict__ dur, float* __restrict__ c,
                            float* __restrict__ out_dur) {
    int b = blockIdx.x;
    int s = threadIdx.x;
    __shared__ float sc[S_];
    float d = dur[b * S_ + s];
    sc[s] = d;
    __syncthreads();
    float v = d;
    for (int off = 1; off < S_; off <<= 1) {
        float add = (s >= off) ? sc[s - off] : 0.f;
        __syncthreads();
        v += add;
        sc[s] = v;
        __syncthreads();
    }
    c[b * S_ + s] = v - 0.5f * d;
    out_dur[b * S_ + s] = d;
}

// ============ Whh -> f16 pair pack: wpk[layer][dir][j][k2] ============
__global__ void whh_pack_kernel(const float* __restrict__ Whh0, const float* __restrict__ Whh1,
                                unsigned* __restrict__ wpk) {
    int idx = blockIdx.x * 256 + threadIdx.x;  // 131072
    int k2 = idx & 63, j = (idx >> 6) & 511, dir = (idx >> 15) & 1, layer = (idx >> 16) & 1;
    const float* W = layer ? Whh1 : Whh0;
    float lo = W[dir * 65536 + j * 128 + 2 * k2];
    float hi = W[dir * 65536 + j * 128 + 2 * k2 + 1];
    U32H2 u;
    u.h = half2_t{(_Float16)lo, (_Float16)hi};
    wpk[idx] = u.u;
}

// ============ gemm: Xg[((dir*512+s)*16+b)*512+jj] = A[m,:256].Wih[n,:256]+bias ============
// A rows m = b*512+s  (x is [B,S,256]; H1 is [b][s][256] -> same row order)
#define BM 64
#define BN 64
#define BK 64
__global__ __launch_bounds__(256) void gemm_xg_kernel(const float* __restrict__ A,
                                                      const float* __restrict__ Bw,
                                                      const float* __restrict__ bias,
                                                      float* __restrict__ Xg) {
    __shared__ float As[BK][BM + 4];
    __shared__ float Bs[BK][BN + 4];
    int tid = threadIdx.x;
    int m0 = blockIdx.x * BM;
    int n0 = blockIdx.y * BN;
    int tm = tid >> 4, tn = tid & 15;
    float acc[4][4] = {};
    for (int k0 = 0; k0 < 256; k0 += BK) {
#pragma unroll
        for (int i = 0; i < 4; i++) {
            int p = tid + 256 * i;
            int m = p >> 4, kq = p & 15;
            float4 av = *reinterpret_cast<const float4*>(&A[(size_t)(m0 + m) * 256 + k0 + 4 * kq]);
            As[4 * kq + 0][m] = av.x; As[4 * kq + 1][m] = av.y;
            As[4 * kq + 2][m] = av.z; As[4 * kq + 3][m] = av.w;
            float4 bv = *reinterpret_cast<const float4*>(&Bw[(size_t)(n0 + m) * 256 + k0 + 4 * kq]);
            Bs[4 * kq + 0][m] = bv.x; Bs[4 * kq + 1][m] = bv.y;
            Bs[4 * kq + 2][m] = bv.z; Bs[4 * kq + 3][m] = bv.w;
        }
        __syncthreads();
#pragma unroll
        for (int k = 0; k < BK; k++) {
            float4 a4 = *reinterpret_cast<const float4*>(&As[k][4 * tm]);
            float4 b4 = *reinterpret_cast<const float4*>(&Bs[k][4 * tn]);
            float av[4] = {a4.x, a4.y, a4.z, a4.w};
            float bv[4] = {b4.x, b4.y, b4.z, b4.w};
#pragma unroll
            for (int i = 0; i < 4; i++)
#pragma unroll
                for (int j = 0; j < 4; j++) acc[i][j] += av[i] * bv[j];
        }
        __syncthreads();
    }
#pragma unroll
    for (int i = 0; i < 4; i++) {
        int m = m0 + 4 * tm + i;
        int b = m >> 9, s = m & 511;
#pragma unroll
        for (int jx = 0; jx < 4; jx++) {
            int n = n0 + 4 * tn + jx;
            int dir = n >> 9, jj = n & 511;
            Xg[((size_t)(dir * 512 + s) * 16 + b) * 512 + jj] = acc[i][jx] + bias[n];
        }
    }
}

// ============ LSTM scan body: one block per (dir,batch); f16 dot2 matvec ============
__device__ void lstm_scan_body(const float* __restrict__ Xg, const unsigned* __restrict__ wpk,
                               float* __restrict__ Hout, char* smem, int blk) {
    int dir = blk >> 4;
    int b = blk & 15;
    int j = threadIdx.x;  // gate row 0..511
    unsigned* hpk = (unsigned*)smem;          // 64 uints = 128 f16 h values
    float* act = (float*)(smem + 256);        // 512 floats

    // per-thread weight row (f16 pairs): 16 x uint4 = 64 VGPRs
    uint4 wv[16];
    const uint4* wrow = (const uint4*)(wpk + ((size_t)dir * 512 + j) * 64);
#pragma unroll
    for (int i = 0; i < 16; i++) wv[i] = wrow[i];

    if (j < 64) hpk[j] = 0;
    float c = 0.f;
    const float* xg_base = Xg + (size_t)dir * (512 * 16 * 512) + (size_t)b * 512;
    int s0 = dir ? 511 : 0;
    float xg = xg_base[(size_t)s0 * 8192 + j];
    __syncthreads();

    for (int t = 0; t < 512; t++) {
        int s = dir ? 511 - t : t;
        int t2 = (t < 511) ? t + 1 : 511;
        int s2 = dir ? 511 - t2 : t2;
        float xg_next = xg_base[(size_t)s2 * 8192 + j];  // prefetch next step
        float acc = xg;
        const uint4* h4 = (const uint4*)hpk;
#pragma unroll
        for (int i = 0; i < 16; i++) {
            uint4 hh = h4[i];  // broadcast read: same addr across lanes
            U32H2 a0, a1, a2, a3, w0, w1, w2, w3;
            a0.u = hh.x; a1.u = hh.y; a2.u = hh.z; a3.u = hh.w;
            w0.u = wv[i].x; w1.u = wv[i].y; w2.u = wv[i].z; w3.u = wv[i].w;
            acc = __builtin_amdgcn_fdot2(a0.h, w0.h, acc, false);
            acc = __builtin_amdgcn_fdot2(a1.h, w1.h, acc, false);
            acc = __builtin_amdgcn_fdot2(a2.h, w2.h, acc, false);
            acc = __builtin_amdgcn_fdot2(a3.h, w3.h, acc, false);
        }
        float a = ((j >> 7) == 2) ? tanhfast(acc) : sigf(acc);
        act[j] = a;
        __syncthreads();
        if (j < 128) {
            float i_ = act[j], f_ = act[128 + j], gg = act[256 + j], o_ = act[384 + j];
            c = f_ * c + i_ * gg;
            float h = o_ * tanhfast(c);
            ((_Float16*)hpk)[j] = (_Float16)h;
            Hout[((size_t)b * 512 + s) * 256 + dir * 128 + j] = h;
        }
        __syncthreads();
        xg = xg_next;
    }
}

// ============ w-write body (fused into layer-0 scan launch) ============
__device__ void wwrite_body(const float* __restrict__ c, const float* __restrict__ w2,
                            float* __restrict__ wout, int gb) {
    int base = (gb * 512 + (int)threadIdx.x) * 8;
    int t0 = base & 2047;
    int bs = base >> 11;
    int b = bs >> 9;
    float cv = c[bs];
    float4 w2a = *(const float4*)&w2[b * 2048 + t0];
    float4 w2b = *(const float4*)&w2[b * 2048 + t0 + 4];
    float r[8];
#pragma unroll
    for (int i = 0; i < 8; i++) {
        float d = (float)(t0 + 1 + i) - cv;
        r[i] = __expf(-0.1f * d * d);
    }
    float4 o1 = {r[0] / w2a.x, r[1] / w2a.y, r[2] / w2a.z, r[3] / w2a.w};
    float4 o2 = {r[4] / w2b.x, r[5] / w2b.y, r[6] / w2b.z, r[7] / w2b.w};
    *(float4*)&wout[base] = o1;
    *(float4*)&wout[base + 4] = o2;
}

// ============ einsum GEMM body, 512 threads, 128(t)x64(d) fp32 tile ============
__device__ void gemm_out_body(const float* __restrict__ wmat, const float* __restrict__ x,
                              float* __restrict__ out, int gb, char* smem) {
    int tt = gb & 15, dd = (gb >> 4) & 3, b = gb >> 6;
    int m0 = tt * 128, n0 = dd * 64;
    float* As = (float*)smem;        // [64][132]
    float* Bs = As + 64 * 132;       // [64][68]
    const float* wb = wmat + (size_t)b * (512 * 2048);
    const float* xb = x + (size_t)b * (512 * 256);
    int tid = threadIdx.x;
    int tm = tid >> 4, tn = tid & 15;
    float acc[4][4] = {};
    for (int k0 = 0; k0 < 512; k0 += 64) {
#pragma unroll
        for (int i = 0; i < 4; i++) {
            int p = tid + 512 * i;
            int kk = p >> 5, mq = p & 31;
            *(float4*)&As[kk * 132 + 4 * mq] =
                *(const float4*)&wb[(size_t)(k0 + kk) * 2048 + m0 + 4 * mq];
        }
#pragma unroll
        for (int i = 0; i < 2; i++) {
            int p = tid + 512 * i;
            int kk = p >> 4, nq = p & 15;
            *(float4*)&Bs[kk * 68 + 4 * nq] =
                *(const float4*)&xb[(size_t)(k0 + kk) * 256 + n0 + 4 * nq];
        }
        __syncthreads();
#pragma unroll
        for (int k = 0; k < 64; k++) {
            float4 a4 = *(const float4*)&As[k * 132 + 4 * tm];
            float4 b4 = *(const float4*)&Bs[k * 68 + 4 * tn];
            float av[4] = {a4.x, a4.y, a4.z, a4.w};
            float bv[4] = {b4.x, b4.y, b4.z, b4.w};
#pragma unroll
            for (int i = 0; i < 4; i++)
#pragma unroll
                for (int j = 0; j < 4; j++) acc[i][j] += av[i] * bv[j];
        }
        __syncthreads();
    }
#pragma unroll
    for (int i = 0; i < 4; i++) {
        int m = m0 + 4 * tm + i;
        float4 o = {acc[i][0], acc[i][1], acc[i][2], acc[i][3]};
        *(float4*)&out[((size_t)b * 2048 + m) * 256 + n0 + 4 * tn] = o;
    }
}

// ============ fused launches (32 scan blocks + filler blocks) ============
__global__ __launch_bounds__(512) void fusedA_kernel(const float* __restrict__ Xg,
                                                     const unsigned* __restrict__ wpk,
                                                     float* __restrict__ H1,
                                                     const float* __restrict__ c,
                                                     const float* __restrict__ w2,
                                                     float* __restrict__ out_w) {
    extern __shared__ char smem[];
    if (blockIdx.x < 32) lstm_scan_body(Xg, wpk, H1, smem, blockIdx.x);
    else wwrite_body(c, w2, out_w, blockIdx.x - 32);
}

__global__ __launch_bounds__(512) void fusedB_kernel(const float* __restrict__ Xg,
                                                     const unsigned* __restrict__ wpk,
                                                     float* __restrict__ H1,
                                                     const float* __restrict__ wmat,
                                                     const float* __restrict__ x,
                                                     float* __restrict__ out_main) {
    extern __shared__ char smem[];
    if (blockIdx.x < 32) lstm_scan_body(Xg, wpk, H1, smem, blockIdx.x);
    else gemm_out_body(wmat, x, out_main, blockIdx.x - 32, smem);
}

// ============ projection: log_dur (H1 [b][s][256]) ============
__global__ void proj_kernel(const float* __restrict__ H2, const float* __restrict__ pw,
                            const float* __restrict__ pb, const unsigned char* __restrict__ mask,
                            float* __restrict__ out) {
    int row = blockIdx.x * 4 + (threadIdx.x >> 6);
    int lane = threadIdx.x & 63;
    float4 h = *reinterpret_cast<const float4*>(&H2[(size_t)row * 256 + lane * 4]);
    float4 w = *reinterpret_cast<const float4*>(&pw[lane * 4]);
    float v = h.x * w.x + h.y * w.y + h.z * w.z + h.w * w.w;
#pragma unroll
    for (int off = 32; off; off >>= 1) v += __shfl_xor(v, off);
    if (lane == 0) {
        float r = v + pb[0];
        r = r > 0.f ? r : 0.f;
        if (mask[row]) r = 0.f;
        out[row] = r;
    }
}

// ============ w2[b,t] = sum_s exp(-0.1 (t+1-c)^2) ============
__global__ void wsum_kernel(const float* __restrict__ c, float* __restrict__ w2) {
    int idx = blockIdx.x * 4 + (threadIdx.x >> 6);
    int lane = threadIdx.x & 63;
    int b = idx >> 11, t = idx & 2047;
    float tv = (float)(t + 1);
    const float* cb = c + b * 512;
    float sum = 0.f;
#pragma unroll
    for (int i = 0; i < 8; i++) {
        float d = tv - cb[lane + 64 * i];
        sum += __expf(-0.1f * d * d);
    }
#pragma unroll
    for (int off = 32; off; off >>= 1) sum += __shfl_xor(sum, off);
    if (lane == 0) w2[idx] = (sum == 0.f) ? 1.f : sum;
}

extern "C" void kernel_launch(void* const* d_in, const int* in_sizes, int n_in,
                              void* d_out, int out_size, void* d_ws, size_t ws_size,
                              hipStream_t stream) {
    const float* x = (const float*)d_in[0];
    const unsigned char* mask = (const unsigned char*)d_in[1];
    const float* dur = (const float*)d_in[2];
    const float* Wih0 = (const float*)d_in[3];
    const float* Whh0 = (const float*)d_in[4];
    const float* b0 = (const float*)d_in[5];
    const float* Wih1 = (const float*)d_in[6];
    const float* Whh1 = (const float*)d_in[7];
    const float* b1 = (const float*)d_in[8];
    const float* pw = (const float*)d_in[9];
    const float* pb = (const float*)d_in[10];

    float* out = (float*)d_out;
    float* ws = (float*)d_ws;
    float* c = ws + WS_C;
    float* w2 = ws + WS_W2;
    unsigned* wpk = (unsigned*)(ws + WS_WPK);
    float* Xg = ws + WS_XG;
    float* H1 = ws + WS_H1;

    float* out_main = out + OUT_MAIN;
    float* out_logdur = out + OUT_LOGDUR;
    float* out_dur = out + OUT_DUR;
    float* out_w = out + OUT_W;

    // ---- prep: centers, duration copy, Whh f16 pack, w2 ----
    prep_kernel<<<16, 512, 0, stream>>>(dur, c, out_dur);
    whh_pack_kernel<<<512, 256, 0, stream>>>(Whh0, Whh1, wpk);
    wsum_kernel<<<8192, 256, 0, stream>>>(c, w2);

    // ---- layer 0: Xg gemm (A = x), then scan fused with w-write ----
    gemm_xg_kernel<<<dim3(128, 16), 256, 0, stream>>>(x, Wih0, b0, Xg);
    fusedA_kernel<<<32 + 4096, 512, 2304, stream>>>(Xg, wpk, H1, c, w2, out_w);

    // ---- layer 1: Xg gemm (A = H1, same row order), then scan fused with einsum ----
    gemm_xg_kernel<<<dim3(128, 16), 256, 0, stream>>>(H1, Wih1, b1, Xg);
    fusedB_kernel<<<32 + 1024, 512, 51200, stream>>>(Xg, wpk + 65536, H1, out_w, x, out_main);

    // ---- projection ----
    proj_kernel<<<2048, 256, 0, stream>>>(H1, pw, pb, mask, out_logdur);
}